// Round 1
// baseline (279.564 us; speedup 1.0000x reference)
//
#include <hip/hip_runtime.h>

// ConvCaps: b=16, A=32, B=32, K=3, P=4, stride=2, h=w=14 -> oh=ow=6
#define BATCH 16
#define AA 32
#define BB 32
#define CC 16
#define DD 16
#define KKA 288
#define OHW 6
#define LL 36
#define NBL 576   // BATCH * LL
#define HH 14
#define WWD 14

// workspace layout (float offsets)
#define PU_OFF    0ull                 // [NBL][KKA][CC]        = 2,654,208
#define AR_OFF    2654208ull           // [NBL][KKA][BB]        = 5,308,416
#define ARSUM_OFF 7962624ull           // [NBL][BB]             = 18,432
#define PRE_OFF   7981056ull           // [512][NBL]            = 294,912
// total 8,275,968 floats = 31.6 MiB

// ---------------------------------------------------------------------------
// Kernel 1: per-patch routing. Computes pose_u (stored to ws), ar, ar_sum,
// and output 0 (a_out).
// ---------------------------------------------------------------------------
__global__ __launch_bounds__(256) void k_routing(
    const float* __restrict__ a, const float* __restrict__ pose,
    const float* __restrict__ W2, const float* __restrict__ b2,
    float* __restrict__ ws, float* __restrict__ out_a)
{
    __shared__ float pu_s[KKA][CC];   // 18 KB
    __shared__ float au_s[KKA];
    __shared__ float red_s[8][BB];
    __shared__ float arsum_s[BB];
    __shared__ float atot_s;

    const int bl = blockIdx.x;
    const int b  = bl / LL;
    const int l  = bl - b * LL;
    const int oy = l / OHW, ox = l - (l / OHW) * OHW;
    const int iy0 = oy * 2, ix0 = ox * 2;
    const int tid = threadIdx.x;

    // stage pose_u: n = kk*32 + aidx; element = pose[b, aidx*16+c, iy0+ki, ix0+kj]
    for (int idx = tid; idx < KKA * CC; idx += 256) {
        int n = idx >> 4, c = idx & 15;
        int aidx = n & 31, kk = n >> 5;
        int ki = kk / 3, kj = kk - ki * 3;
        float v = pose[(((size_t)b * 512 + (size_t)aidx * 16 + c) * HH + (iy0 + ki)) * WWD + (ix0 + kj)];
        pu_s[n][c] = v;
        ws[PU_OFF + ((size_t)bl * KKA + n) * CC + c] = v;
    }
    for (int n = tid; n < KKA; n += 256) {
        int aidx = n & 31, kk = n >> 5;
        int ki = kk / 3, kj = kk - ki * 3;
        au_s[n] = a[(((size_t)b * AA + aidx) * HH + (iy0 + ki)) * WWD + (ix0 + kj)];
    }
    __syncthreads();

    const int j = tid & 31;     // capsule index (softmax axis)
    const int g = tid >> 5;     // n-subgroup 0..7
    float arsum_p = 0.f;
    for (int it = 0; it < KKA / 8; ++it) {
        int n = it * 8 + g;
        const float4* w2v = reinterpret_cast<const float4*>(W2 + ((size_t)n * BB + j) * CC);
        const float4* puv = reinterpret_cast<const float4*>(&pu_s[n][0]);
        float4 w0 = w2v[0], w1 = w2v[1], w2r = w2v[2], w3 = w2v[3];
        float4 p0 = puv[0], p1 = puv[1], p2 = puv[2], p3 = puv[3];
        float lg = b2[(size_t)n * BB + j]
            + w0.x*p0.x + w0.y*p0.y + w0.z*p0.z + w0.w*p0.w
            + w1.x*p1.x + w1.y*p1.y + w1.z*p1.z + w1.w*p1.w
            + w2r.x*p2.x + w2r.y*p2.y + w2r.z*p2.z + w2r.w*p2.w
            + w3.x*p3.x + w3.y*p3.y + w3.z*p3.z + w3.w*p3.w;
        // softmax over the 32 lanes of this half-wave (j axis)
        float m = lg;
        #pragma unroll
        for (int msk = 16; msk >= 1; msk >>= 1)
            m = fmaxf(m, __shfl_xor(m, msk));
        float e = __expf(lg - m);
        float s = e;
        #pragma unroll
        for (int msk = 16; msk >= 1; msk >>= 1)
            s += __shfl_xor(s, msk);
        float ar = au_s[n] * (e / s);
        ws[AR_OFF + ((size_t)bl * KKA + n) * BB + j] = ar;
        arsum_p += ar;
    }
    red_s[g][j] = arsum_p;
    __syncthreads();
    if (tid < 32) {
        float s = 0.f;
        #pragma unroll
        for (int gg = 0; gg < 8; ++gg) s += red_s[gg][tid];
        arsum_s[tid] = s;
        ws[ARSUM_OFF + (size_t)bl * BB + tid] = s;
    }
    if (tid < 64) {
        float p = 0.f;
        for (int n = tid; n < KKA; n += 64) p += au_s[n];
        #pragma unroll
        for (int msk = 32; msk >= 1; msk >>= 1) p += __shfl_xor(p, msk);
        if (tid == 0) atot_s = p;
    }
    __syncthreads();
    if (tid < 32) {
        out_a[((size_t)b * BB + tid) * LL + l] = arsum_s[tid] / atot_s;
    }
}

// ---------------------------------------------------------------------------
// Kernel 2: pose contraction. pre[ch=j*16+d][bl] =
//   (Sum_n ar[bl,n,j] * Sum_c W1[n, j*16+d, c] * pu[bl,n,c]) / ar_sum[bl,j]
// grid = (NBL/24 bl-tiles, 16 j-tiles of 2 capsules each)
// ---------------------------------------------------------------------------
#define BLT 24
#define NCH 16

__global__ __launch_bounds__(256) void k_pose(
    const float* __restrict__ W1, float* __restrict__ ws)
{
    __shared__ float pu_s[NCH][BLT][CC];   // 24 KB

    const int bl0 = blockIdx.x * BLT;
    const int jt  = blockIdx.y;            // 0..15 (pair of capsules)
    const int tid = threadIdx.x;
    const int col = tid & 31;              // j2*16 + d
    const int j2  = col >> 4;
    const int r0  = (tid >> 5) * 3;        // 3 bl rows per thread

    const float* pu    = ws + PU_OFF;
    const float* arw   = ws + AR_OFF;
    const float* arsum = ws + ARSUM_OFF;
    float*       pre   = ws + PRE_OFF;

    float acc[3] = {0.f, 0.f, 0.f};

    for (int n0 = 0; n0 < KKA; n0 += NCH) {
        // stage pu chunk: NCH n's x BLT rows x 16 c = 1536 float4, 6/thread
        #pragma unroll
        for (int k = 0; k < 6; ++k) {
            int i = tid + k * 256;
            int nn = i / 96;               // 96 float4 per n
            int rem = i - nn * 96;
            int blr = rem >> 2;
            int c4 = (rem & 3) * 4;
            float4 v = *reinterpret_cast<const float4*>(
                pu + ((size_t)(bl0 + blr) * KKA + (n0 + nn)) * CC + c4);
            *reinterpret_cast<float4*>(&pu_s[nn][blr][c4]) = v;
        }
        __syncthreads();
        #pragma unroll 4
        for (int nn = 0; nn < NCH; ++nn) {
            const int n = n0 + nn;
            const float4* w1v = reinterpret_cast<const float4*>(
                W1 + ((size_t)n * 512 + jt * 32 + col) * CC);
            float4 w0 = w1v[0], w1r = w1v[1], w2r = w1v[2], w3r = w1v[3];
            #pragma unroll
            for (int rr = 0; rr < 3; ++rr) {
                int blr = r0 + rr;
                const float4* pv = reinterpret_cast<const float4*>(&pu_s[nn][blr][0]);
                float4 p0 = pv[0], p1 = pv[1], p2 = pv[2], p3 = pv[3];
                float s =
                    w0.x*p0.x + w0.y*p0.y + w0.z*p0.z + w0.w*p0.w +
                    w1r.x*p1.x + w1r.y*p1.y + w1r.z*p1.z + w1r.w*p1.w +
                    w2r.x*p2.x + w2r.y*p2.y + w2r.z*p2.z + w2r.w*p2.w +
                    w3r.x*p3.x + w3r.y*p3.y + w3r.z*p3.z + w3r.w*p3.w;
                float arv = arw[((size_t)(bl0 + blr) * KKA + n) * BB + jt * 2 + j2];
                acc[rr] += arv * s;
            }
        }
        __syncthreads();
    }
    const int ch = jt * 32 + col;
    #pragma unroll
    for (int rr = 0; rr < 3; ++rr) {
        int blg = bl0 + r0 + rr;
        float asum = arsum[(size_t)blg * BB + jt * 2 + j2];
        pre[(size_t)ch * NBL + blg] = acc[rr] / asum;
    }
}

// ---------------------------------------------------------------------------
// Kernel 3: BatchNorm (training-mode batch stats, biased var) + layout to
// output [b, 512, 6, 6]. One wave per channel, 4 channels per block.
// ---------------------------------------------------------------------------
__global__ __launch_bounds__(256) void k_bn(
    const float* __restrict__ ws, const float* __restrict__ gamma,
    const float* __restrict__ beta, float* __restrict__ out_pose)
{
    const int tid  = threadIdx.x;
    const int wid  = tid >> 6, lane = tid & 63;
    const int ch   = blockIdx.x * 4 + wid;
    const float* row = ws + PRE_OFF + (size_t)ch * NBL;

    float sum = 0.f, sq = 0.f;
    float v[9];
    #pragma unroll
    for (int k = 0; k < 9; ++k) {
        float x = row[lane + k * 64];
        v[k] = x;
        sum += x;
        sq  += x * x;
    }
    #pragma unroll
    for (int msk = 32; msk >= 1; msk >>= 1) {
        sum += __shfl_xor(sum, msk);
        sq  += __shfl_xor(sq, msk);
    }
    const float mean = sum * (1.f / 576.f);
    const float var  = sq * (1.f / 576.f) - mean * mean;
    const float inv  = rsqrtf(var + 1e-5f);
    const float sc   = gamma[ch] * inv;
    const float sh   = beta[ch] - mean * sc;
    #pragma unroll
    for (int k = 0; k < 9; ++k) {
        int i = lane + k * 64;
        int b = i / 36;
        int l = i - b * 36;
        out_pose[(size_t)b * 18432 + (size_t)ch * 36 + l] = v[k] * sc + sh;
    }
}

extern "C" void kernel_launch(void* const* d_in, const int* in_sizes, int n_in,
                              void* d_out, int out_size, void* d_ws, size_t ws_size,
                              hipStream_t stream)
{
    const float* a     = (const float*)d_in[0];
    const float* pose  = (const float*)d_in[1];
    const float* W1    = (const float*)d_in[2];
    const float* W2    = (const float*)d_in[3];
    const float* b2    = (const float*)d_in[4];
    const float* gamma = (const float*)d_in[5];
    const float* beta  = (const float*)d_in[6];
    float* out      = (float*)d_out;
    float* ws       = (float*)d_ws;
    float* out_a    = out;              // [16, 32, 6, 6] = 18432
    float* out_pose = out + 18432;      // [16, 512, 6, 6] = 294912

    hipLaunchKernelGGL(k_routing, dim3(NBL), dim3(256), 0, stream,
                       a, pose, W2, b2, ws, out_a);
    hipLaunchKernelGGL(k_pose, dim3(NBL / BLT, 16), dim3(256), 0, stream, W1, ws);
    hipLaunchKernelGGL(k_bn, dim3(128), dim3(256), 0, stream, ws, gamma, beta, out_pose);
}

// Round 2
// 113.115 us; speedup vs baseline: 2.4715x; 2.4715x over previous
//
#include <hip/hip_runtime.h>

// ConvCaps: b=16, A=32, B=32, K=3, P=4, stride=2, h=w=14 -> oh=ow=6
#define AA 32
#define BB 32
#define CC 16
#define KKA 288
#define OHW 6
#define LL 36
#define NBL 576   // BATCH * LL
#define HH 14
#define WWD 14

// workspace layout (ushort/float element offsets)
#define W1B_OFF   0ull                       // bf16 [288][512][16]  = 2,359,296 ush
#define PU16_OFF  2359296ull                 // bf16 [576][288][16]  = 2,654,208 ush
#define ARN16_OFF 5013504ull                 // bf16 [576][288][32]  = 5,308,416 ush
#define PRE_BYTE  20643840ull                // f32  [512][576]      = 294,912 f
// total ~21.8 MB

typedef __attribute__((ext_vector_type(8))) short bf16x8;
typedef __attribute__((ext_vector_type(4))) float f32x4;

__device__ __forceinline__ unsigned short f2b(float f) {
    unsigned int u = __builtin_bit_cast(unsigned int, f);
    u += 0x7fffu + ((u >> 16) & 1u);             // RNE
    return (unsigned short)(u >> 16);
}

// ---------------------------------------------------------------------------
// Kernel 0: W1 fp32 -> bf16
// ---------------------------------------------------------------------------
__global__ __launch_bounds__(256) void k_w1cvt(
    const float* __restrict__ W1, unsigned short* __restrict__ W1b)
{
    size_t i = ((size_t)blockIdx.x * 256 + threadIdx.x) * 8;
    float4 v0 = *reinterpret_cast<const float4*>(W1 + i);
    float4 v1 = *reinterpret_cast<const float4*>(W1 + i + 4);
    uint4 o;
    o.x = (unsigned)f2b(v0.x) | ((unsigned)f2b(v0.y) << 16);
    o.y = (unsigned)f2b(v0.z) | ((unsigned)f2b(v0.w) << 16);
    o.z = (unsigned)f2b(v1.x) | ((unsigned)f2b(v1.y) << 16);
    o.w = (unsigned)f2b(v1.z) | ((unsigned)f2b(v1.w) << 16);
    *reinterpret_cast<uint4*>(W1b + i) = o;
}

// ---------------------------------------------------------------------------
// Kernel 1: per-patch routing. Emits bf16 pose_u, bf16 NORMALIZED arn
// (= a_u * softmax / ar_sum), and output 0 (a_out).
// ---------------------------------------------------------------------------
__global__ __launch_bounds__(256) void k_routing(
    const float* __restrict__ a, const float* __restrict__ pose,
    const float* __restrict__ W2, const float* __restrict__ b2,
    unsigned short* __restrict__ pu16w, unsigned short* __restrict__ arn16w,
    float* __restrict__ out_a)
{
    __shared__ float pu_s[KKA][CC];   // 18 KB
    __shared__ float au_s[KKA];
    __shared__ float red_s[8][BB];
    __shared__ float arsum_s[BB];
    __shared__ float atot_s;

    const int bl = blockIdx.x;
    const int b  = bl / LL;
    const int l  = bl - b * LL;
    const int oy = l / OHW, ox = l - (l / OHW) * OHW;
    const int iy0 = oy * 2, ix0 = ox * 2;
    const int tid = threadIdx.x;

    for (int idx = tid; idx < KKA * CC; idx += 256) {
        int n = idx >> 4, c = idx & 15;
        int aidx = n & 31, kk = n >> 5;
        int ki = kk / 3, kj = kk - ki * 3;
        float v = pose[(((size_t)b * 512 + (size_t)aidx * 16 + c) * HH + (iy0 + ki)) * WWD + (ix0 + kj)];
        pu_s[n][c] = v;
        pu16w[((size_t)bl * KKA + n) * CC + c] = f2b(v);
    }
    for (int n = tid; n < KKA; n += 256) {
        int aidx = n & 31, kk = n >> 5;
        int ki = kk / 3, kj = kk - ki * 3;
        au_s[n] = a[(((size_t)b * AA + aidx) * HH + (iy0 + ki)) * WWD + (ix0 + kj)];
    }
    __syncthreads();

    const int j = tid & 31;     // capsule index (softmax axis)
    const int g = tid >> 5;     // n-subgroup 0..7
    float ar_r[36];
    float arsum_p = 0.f;
    #pragma unroll
    for (int it = 0; it < 36; ++it) {
        int n = it * 8 + g;
        const float4* w2v = reinterpret_cast<const float4*>(W2 + ((size_t)n * BB + j) * CC);
        const float4* puv = reinterpret_cast<const float4*>(&pu_s[n][0]);
        float4 w0 = w2v[0], w1 = w2v[1], w2r = w2v[2], w3 = w2v[3];
        float4 p0 = puv[0], p1 = puv[1], p2 = puv[2], p3 = puv[3];
        float lg = b2[(size_t)n * BB + j]
            + w0.x*p0.x + w0.y*p0.y + w0.z*p0.z + w0.w*p0.w
            + w1.x*p1.x + w1.y*p1.y + w1.z*p1.z + w1.w*p1.w
            + w2r.x*p2.x + w2r.y*p2.y + w2r.z*p2.z + w2r.w*p2.w
            + w3.x*p3.x + w3.y*p3.y + w3.z*p3.z + w3.w*p3.w;
        float m = lg;
        #pragma unroll
        for (int msk = 16; msk >= 1; msk >>= 1)
            m = fmaxf(m, __shfl_xor(m, msk));
        float e = __expf(lg - m);
        float s = e;
        #pragma unroll
        for (int msk = 16; msk >= 1; msk >>= 1)
            s += __shfl_xor(s, msk);
        float ar = au_s[n] * (e / s);
        ar_r[it] = ar;
        arsum_p += ar;
    }
    red_s[g][j] = arsum_p;
    __syncthreads();
    if (tid < 32) {
        float s = 0.f;
        #pragma unroll
        for (int gg = 0; gg < 8; ++gg) s += red_s[gg][tid];
        arsum_s[tid] = s;
    }
    if (tid < 64) {
        float p = 0.f;
        for (int n = tid; n < KKA; n += 64) p += au_s[n];
        #pragma unroll
        for (int msk = 32; msk >= 1; msk >>= 1) p += __shfl_xor(p, msk);
        if (tid == 0) atot_s = p;
    }
    __syncthreads();

    const float inv = 1.0f / arsum_s[j];
    #pragma unroll
    for (int it = 0; it < 36; ++it) {
        int n = it * 8 + g;
        arn16w[((size_t)bl * KKA + n) * BB + j] = f2b(ar_r[it] * inv);
    }
    if (tid < 32) {
        out_a[((size_t)b * BB + tid) * LL + l] = arsum_s[tid] / atot_s;
    }
}

// ---------------------------------------------------------------------------
// Kernel 2: MFMA pose contraction. Per capsule j:
//   pre[j*16+d][bl] = sum_{n,c} W1b[n][j*16+d][c] * (arn[bl,n,j]*pu[bl,n,c])
// Block: 16-bl tile x j-pair; 4 waves = 2 j x 2 K-halves (n 0..143 / 144..287).
// ---------------------------------------------------------------------------
__global__ __launch_bounds__(256) void k_pose_mfma(
    const unsigned short* __restrict__ W1b,
    const unsigned short* __restrict__ pu16,
    const unsigned short* __restrict__ arn16,
    float* __restrict__ pre)
{
    __shared__ unsigned long long pu_s8[2][16][64];   // 16 KB, XOR-swizzled rows
    __shared__ unsigned int arn_s[16][289];           // 18.5 KB (pad 288->289)
    __shared__ float red_s[2][256];                   // 2 KB

    const int bl0 = blockIdx.x * 16;
    const int jp  = blockIdx.y;           // j-pair 0..15
    const int tid = threadIdx.x;
    const int w   = tid >> 6;
    const int l   = tid & 63;
    const int jl  = w >> 1;               // j within pair
    const int h   = w & 1;                // K-half
    const int g   = l >> 4;               // lane quarter
    const int d   = l & 15;               // A-row / B-col(bl) / C-col
    const int jg  = jp * 2 + jl;
    const int gh  = g >> 1;               // n offset within pair
    const int co  = (g & 1) * 8;          // c offset

    // stage arn (uint packs j-pair), layout [bl][n] padded
    for (int t = tid; t < 16 * KKA; t += 256) {
        int blr = t / KKA, n = t - blr * KKA;
        arn_s[blr][n] = *reinterpret_cast<const unsigned int*>(
            arn16 + (((size_t)(bl0 + blr) * KKA + n) * BB + jp * 2));
    }

    f32x4 acc0 = {0.f, 0.f, 0.f, 0.f}, acc1 = {0.f, 0.f, 0.f, 0.f};

    for (int ci = 0; ci < 9; ++ci) {
        const int nA = ci * 16, nB = (ci + 9) * 16;
        // stage two pu chunks: [half][16 bl][16 n x 16 c bf16 = 512 B/row]
        for (int t = tid; t < 2048; t += 256) {
            int half = t >> 10, r = t & 1023, blr = r >> 6, q = r & 63;
            int n0 = half ? nB : nA;
            uint2 v = *reinterpret_cast<const uint2*>(
                pu16 + (((size_t)(bl0 + blr) * KKA + n0) * CC + q * 4));
            *reinterpret_cast<uint2*>(&pu_s8[half][blr][q ^ ((blr & 7) << 1)]) = v;
        }
        __syncthreads();
        const int nbase = h ? nB : nA;
        #pragma unroll
        for (int sp = 0; sp < 8; ++sp) {
            const int nl = sp * 2 + gh;
            const int n  = nbase + nl;
            // A-frag: 8 contiguous bf16 along c from global (L2-hot W1 slice)
            uint4 a4 = *reinterpret_cast<const uint4*>(
                W1b + (((size_t)n * 512 + jg * 16 + d) * CC + co));
            // arn scalar for (bl=d, n, jg)
            unsigned int av = arn_s[d][n];
            float s = __builtin_bit_cast(float,
                jl ? (av & 0xffff0000u) : (av << 16));
            // B-frag source: swizzled ds_read_b128 (8 bf16 of pu)
            int byteoff = ((sp * 64 + g * 16) ^ ((d & 7) << 4));
            const uint4 p4 = *reinterpret_cast<const uint4*>(
                reinterpret_cast<const char*>(&pu_s8[h][d][0]) + byteoff);
            uint4 bb;
            {
                unsigned int u = p4.x;
                float lo = __builtin_bit_cast(float, u << 16) * s;
                float hi = __builtin_bit_cast(float, u & 0xffff0000u) * s;
                bb.x = (unsigned)f2b(lo) | ((unsigned)f2b(hi) << 16);
                u = p4.y;
                lo = __builtin_bit_cast(float, u << 16) * s;
                hi = __builtin_bit_cast(float, u & 0xffff0000u) * s;
                bb.y = (unsigned)f2b(lo) | ((unsigned)f2b(hi) << 16);
                u = p4.z;
                lo = __builtin_bit_cast(float, u << 16) * s;
                hi = __builtin_bit_cast(float, u & 0xffff0000u) * s;
                bb.z = (unsigned)f2b(lo) | ((unsigned)f2b(hi) << 16);
                u = p4.w;
                lo = __builtin_bit_cast(float, u << 16) * s;
                hi = __builtin_bit_cast(float, u & 0xffff0000u) * s;
                bb.w = (unsigned)f2b(lo) | ((unsigned)f2b(hi) << 16);
            }
            bf16x8 afrag = __builtin_bit_cast(bf16x8, a4);
            bf16x8 bfrag = __builtin_bit_cast(bf16x8, bb);
            if (sp & 1) acc1 = __builtin_amdgcn_mfma_f32_16x16x32_bf16(afrag, bfrag, acc1, 0, 0, 0);
            else        acc0 = __builtin_amdgcn_mfma_f32_16x16x32_bf16(afrag, bfrag, acc0, 0, 0, 0);
        }
        __syncthreads();
    }

    f32x4 acc = acc0 + acc1;
    if (h == 1) {
        #pragma unroll
        for (int i = 0; i < 4; ++i)
            red_s[jl][(g * 4 + i) * 16 + d] = acc[i];
    }
    __syncthreads();
    if (h == 0) {
        #pragma unroll
        for (int i = 0; i < 4; ++i) {
            float v = acc[i] + red_s[jl][(g * 4 + i) * 16 + d];
            pre[(size_t)(jg * 16 + g * 4 + i) * NBL + bl0 + d] = v;
        }
    }
}

// ---------------------------------------------------------------------------
// Kernel 3: BatchNorm (batch stats, biased var) + layout to [b, 512, 6, 6].
// ---------------------------------------------------------------------------
__global__ __launch_bounds__(256) void k_bn(
    const float* __restrict__ pre, const float* __restrict__ gamma,
    const float* __restrict__ beta, float* __restrict__ out_pose)
{
    const int tid  = threadIdx.x;
    const int wid  = tid >> 6, lane = tid & 63;
    const int ch   = blockIdx.x * 4 + wid;
    const float* row = pre + (size_t)ch * NBL;

    float sum = 0.f, sq = 0.f;
    float v[9];
    #pragma unroll
    for (int k = 0; k < 9; ++k) {
        float x = row[lane + k * 64];
        v[k] = x;
        sum += x;
        sq  += x * x;
    }
    #pragma unroll
    for (int msk = 32; msk >= 1; msk >>= 1) {
        sum += __shfl_xor(sum, msk);
        sq  += __shfl_xor(sq, msk);
    }
    const float mean = sum * (1.f / 576.f);
    const float var  = sq * (1.f / 576.f) - mean * mean;
    const float inv  = rsqrtf(var + 1e-5f);
    const float sc   = gamma[ch] * inv;
    const float sh   = beta[ch] - mean * sc;
    #pragma unroll
    for (int k = 0; k < 9; ++k) {
        int i = lane + k * 64;
        int b = i / 36;
        int l = i - b * 36;
        out_pose[(size_t)b * 18432 + (size_t)ch * 36 + l] = v[k] * sc + sh;
    }
}

extern "C" void kernel_launch(void* const* d_in, const int* in_sizes, int n_in,
                              void* d_out, int out_size, void* d_ws, size_t ws_size,
                              hipStream_t stream)
{
    const float* a     = (const float*)d_in[0];
    const float* pose  = (const float*)d_in[1];
    const float* W1    = (const float*)d_in[2];
    const float* W2    = (const float*)d_in[3];
    const float* b2    = (const float*)d_in[4];
    const float* gamma = (const float*)d_in[5];
    const float* beta  = (const float*)d_in[6];
    float* out      = (float*)d_out;
    float* out_a    = out;              // [16, 32, 6, 6] = 18432
    float* out_pose = out + 18432;      // [16, 512, 6, 6] = 294912

    unsigned short* wsu = (unsigned short*)d_ws;
    unsigned short* W1b   = wsu + W1B_OFF;
    unsigned short* pu16  = wsu + PU16_OFF;
    unsigned short* arn16 = wsu + ARN16_OFF;
    float* pre = (float*)((char*)d_ws + PRE_BYTE);

    hipLaunchKernelGGL(k_w1cvt, dim3(1152), dim3(256), 0, stream, W1, W1b);
    hipLaunchKernelGGL(k_routing, dim3(NBL), dim3(256), 0, stream,
                       a, pose, W2, b2, pu16, arn16, out_a);
    hipLaunchKernelGGL(k_pose_mfma, dim3(36, 16), dim3(256), 0, stream,
                       W1b, pu16, arn16, pre);
    hipLaunchKernelGGL(k_bn, dim3(128), dim3(256), 0, stream, pre, gamma, beta, out_pose);
}

// Round 3
// 57.310 us; speedup vs baseline: 4.8781x; 1.9738x over previous
//
#include <hip/hip_runtime.h>

// ConvCaps: b=16, A=32, B=32, K=3, P=4, stride=2, h=w=14 -> oh=ow=6
#define AA 32
#define BB 32
#define CC 16
#define KKA 288
#define OHW 6
#define LL 36
#define NBL 576
#define HH 14
#define WWD 14

// ---- workspace layout ----
// ushort region (from byte 0):
#define W1B_OFF   0ull          // bf16 [288][512][16] = 2,359,296
#define W2B_OFF   2359296ull    // bf16 [288][32][16]  =   147,456
#define PU16_OFF  2506752ull    // bf16 [576][288][16] = 2,654,208
#define AR16_OFF  5160960ull    // bf16 [576][288][32] = 5,308,416
// float region starts at byte 20,938,752:
#define FREG_BYTE 20938752ull
#define AU_F      0ull          // f32 [576][288]      = 165,888
#define ARSUMP_F  165888ull     // f32 [36][576][32]   = 663,552
#define ARSUM_F   829440ull     // f32 [576][32]       =  18,432
#define PREP_F    847872ull     // f32 [2][512][576]   = 589,824
// total ~26.7 MB (fits: R1 used 33 MB successfully)

typedef __attribute__((ext_vector_type(8))) short bf16x8;
typedef __attribute__((ext_vector_type(4))) float f32x4;

__device__ __forceinline__ unsigned cvtpk(float lo, float hi) {
    unsigned r;
    asm("v_cvt_pk_bf16_f32 %0, %1, %2" : "=v"(r) : "v"(lo), "v"(hi));
    return r;
}
__device__ __forceinline__ float blo(unsigned u) {
    return __builtin_bit_cast(float, u << 16);
}
__device__ __forceinline__ float bhi(unsigned u) {
    return __builtin_bit_cast(float, u & 0xffff0000u);
}

// ---------------------------------------------------------------------------
// Kernel 0: W1 and W2 fp32 -> bf16 (streaming)
// ---------------------------------------------------------------------------
__global__ __launch_bounds__(256) void k_cvt(
    const float* __restrict__ W1, const float* __restrict__ W2,
    unsigned short* __restrict__ W1b, unsigned short* __restrict__ W2b)
{
    size_t i = ((size_t)blockIdx.x * 256 + threadIdx.x) * 8;
    const float* src;
    unsigned short* dst;
    if (i < 2359296ull) { src = W1 + i; dst = W1b + i; }
    else { src = W2 + (i - 2359296ull); dst = W2b + (i - 2359296ull); }
    float4 v0 = *reinterpret_cast<const float4*>(src);
    float4 v1 = *reinterpret_cast<const float4*>(src + 4);
    uint4 o;
    o.x = cvtpk(v0.x, v0.y);
    o.y = cvtpk(v0.z, v0.w);
    o.z = cvtpk(v1.x, v1.y);
    o.w = cvtpk(v1.z, v1.w);
    *reinterpret_cast<uint4*>(dst) = o;
}

// ---------------------------------------------------------------------------
// Kernel 1: gather. Block = (b, aidx). Stages contiguous pose slice in LDS,
// scatters bf16 pu16[bl][n][c] and f32 au[bl][n].
// ---------------------------------------------------------------------------
__global__ __launch_bounds__(256) void k_gather(
    const float* __restrict__ a, const float* __restrict__ pose,
    unsigned short* __restrict__ pu16, float* __restrict__ auf)
{
    __shared__ float ps[16][196];   // 12.25 KB
    __shared__ float as_[196];
    const int blk = blockIdx.x;
    const int b = blk >> 5, aidx = blk & 31;
    const int tid = threadIdx.x;

    const float* psrc = pose + ((size_t)b * 512 + (size_t)aidx * 16) * 196;
    for (int t = tid; t < 3136; t += 256) ((float*)ps)[t] = psrc[t];
    const float* asrc = a + ((size_t)b * 32 + aidx) * 196;
    if (tid < 196) as_[tid] = asrc[tid];
    __syncthreads();

    // pu16 writes: 2592 uints (c-pairs)
    for (int t = tid; t < 2592; t += 256) {
        int c2 = t & 7;
        int kk = (t >> 3) % 9;
        int l  = t / 72;
        int oy = l / 6, ox = l - (l / 6) * 6;
        int ki = kk / 3, kj = kk - (kk / 3) * 3;
        int pix = (oy * 2 + ki) * 14 + ox * 2 + kj;
        unsigned v = cvtpk(ps[c2 * 2][pix], ps[c2 * 2 + 1][pix]);
        *reinterpret_cast<unsigned*>(
            pu16 + (((size_t)(b * 36 + l)) * KKA + kk * 32 + aidx) * 16 + c2 * 2) = v;
    }
    for (int t = tid; t < 324; t += 256) {
        int kk = t % 9, l = t / 9;
        int oy = l / 6, ox = l - (l / 6) * 6;
        int ki = kk / 3, kj = kk - (kk / 3) * 3;
        auf[((size_t)(b * 36 + l)) * KKA + kk * 32 + aidx] =
            as_[(oy * 2 + ki) * 14 + ox * 2 + kj];
    }
}

// ---------------------------------------------------------------------------
// Kernel 2: logits via zero-padded 16x16x32 MFMA + in-register softmax.
// Grid (36 bl-tiles, 9 n-ranges of 32); 4 waves each own 8 n.
// Writes unnormalized ar16[bl][n][j] (bf16) and arsum partials [36][576][32].
// ---------------------------------------------------------------------------
__global__ __launch_bounds__(256) void k_logit(
    const unsigned short* __restrict__ W2b, const unsigned short* __restrict__ pu16,
    const float* __restrict__ b2, const float* __restrict__ auf,
    unsigned short* __restrict__ ar16, float* __restrict__ arsump)
{
    __shared__ float b2_s[32][32];    // 4 KB
    __shared__ float au_s[16][33];    // 2.1 KB (padded)
    const int bl0 = blockIdx.x * 16;
    const int n0b = blockIdx.y * 32;
    const int tid = threadIdx.x;

    #pragma unroll
    for (int k = 0; k < 4; ++k) {
        int t = tid + k * 256;
        b2_s[t >> 5][t & 31] = b2[(size_t)(n0b + (t >> 5)) * 32 + (t & 31)];
    }
    #pragma unroll
    for (int k = 0; k < 2; ++k) {
        int t = tid + k * 256;
        au_s[t >> 5][t & 31] = auf[((size_t)(bl0 + (t >> 5))) * KKA + n0b + (t & 31)];
    }
    __syncthreads();

    const int w = tid >> 6, lane = tid & 63;
    const int g = lane >> 4, d = lane & 15;
    float asum[8] = {0.f, 0.f, 0.f, 0.f, 0.f, 0.f, 0.f, 0.f};

    for (int nn = 0; nn < 8; ++nn) {
        const int nl = w * 8 + nn;
        const int n  = n0b + nl;
        uint4 a0 = {0, 0, 0, 0}, a1 = {0, 0, 0, 0}, bbv = {0, 0, 0, 0};
        if (g < 2) {
            a0 = *reinterpret_cast<const uint4*>(W2b + ((size_t)n * 32 + d) * 16 + g * 8);
            a1 = *reinterpret_cast<const uint4*>(W2b + ((size_t)n * 32 + 16 + d) * 16 + g * 8);
            bbv = *reinterpret_cast<const uint4*>(
                pu16 + (((size_t)(bl0 + d)) * KKA + n) * 16 + g * 8);
        }
        f32x4 zero = {0.f, 0.f, 0.f, 0.f};
        f32x4 c0 = __builtin_amdgcn_mfma_f32_16x16x32_bf16(
            __builtin_bit_cast(bf16x8, a0), __builtin_bit_cast(bf16x8, bbv), zero, 0, 0, 0);
        f32x4 c1 = __builtin_amdgcn_mfma_f32_16x16x32_bf16(
            __builtin_bit_cast(bf16x8, a1), __builtin_bit_cast(bf16x8, bbv), zero, 0, 0, 0);

        float v[8];
        #pragma unroll
        for (int i = 0; i < 4; ++i) {
            v[i]     = c0[i] + b2_s[nl][g * 4 + i];
            v[4 + i] = c1[i] + b2_s[nl][16 + g * 4 + i];
        }
        float m = v[0];
        #pragma unroll
        for (int i = 1; i < 8; ++i) m = fmaxf(m, v[i]);
        m = fmaxf(m, __shfl_xor(m, 16));
        m = fmaxf(m, __shfl_xor(m, 32));
        float s = 0.f;
        #pragma unroll
        for (int i = 0; i < 8; ++i) { v[i] = __expf(v[i] - m); s += v[i]; }
        s += __shfl_xor(s, 16);
        s += __shfl_xor(s, 32);
        const float scale = au_s[d][nl] / s;
        float p[8];
        #pragma unroll
        for (int i = 0; i < 8; ++i) { p[i] = v[i] * scale; asum[i] += p[i]; }

        unsigned short* dst = ar16 + (((size_t)(bl0 + d)) * KKA + n) * 32;
        uint2 u0, u1;
        u0.x = cvtpk(p[0], p[1]); u0.y = cvtpk(p[2], p[3]);
        u1.x = cvtpk(p[4], p[5]); u1.y = cvtpk(p[6], p[7]);
        *reinterpret_cast<uint2*>(dst + g * 4) = u0;
        *reinterpret_cast<uint2*>(dst + 16 + g * 4) = u1;
    }
    float* ap = arsump + ((size_t)(blockIdx.y * 4 + w)) * 18432 + ((size_t)(bl0 + d)) * 32;
    float4 s0 = {asum[0], asum[1], asum[2], asum[3]};
    float4 s1 = {asum[4], asum[5], asum[6], asum[7]};
    *reinterpret_cast<float4*>(ap + g * 4) = s0;
    *reinterpret_cast<float4*>(ap + 16 + g * 4) = s1;
}

// ---------------------------------------------------------------------------
// Kernel 3: finish routing — arsum = sum of 36 partials; a_out = arsum/au_tot.
// ---------------------------------------------------------------------------
__global__ __launch_bounds__(256) void k_finish(
    const float* __restrict__ arsump, const float* __restrict__ auf,
    float* __restrict__ arsum, float* __restrict__ out_a)
{
    const int tid = threadIdx.x;
    const int wid = tid >> 6, lane = tid & 63;
    const int bl = blockIdx.x * 4 + wid;
    const int j = lane & 31, h = lane >> 5;

    float s = 0.f;
    #pragma unroll
    for (int k = 0; k < 18; ++k) {
        int r = h * 18 + k;
        s += arsump[(size_t)r * 18432 + (size_t)bl * 32 + j];
    }
    s += __shfl_xor(s, 32);

    float at = 0.f;
    #pragma unroll
    for (int k = 0; k < 5; ++k) {
        int n = k * 64 + lane;
        if (n < KKA) at += auf[(size_t)bl * KKA + n];
    }
    #pragma unroll
    for (int m = 1; m <= 32; m <<= 1) at += __shfl_xor(at, m);

    if (lane < 32) {
        arsum[(size_t)bl * 32 + j] = s;
        int b = bl / 36, l = bl - (bl / 36) * 36;
        out_a[((size_t)b * 32 + j) * 36 + l] = s / at;
    }
}

// ---------------------------------------------------------------------------
// Kernel 4: MFMA pose contraction, K-split across blocks.
// Grid (36 bl-tiles, 16 j-pairs, 2 K-halves); 4 waves = 2 j x 2 sub-halves.
// pre_part[z][ch][bl] = (sum over z-range of ar*W1*pu) / arsum[bl][j]
// ---------------------------------------------------------------------------
__global__ __launch_bounds__(256) void k_pose(
    const unsigned short* __restrict__ W1b, const unsigned short* __restrict__ pu16,
    const unsigned short* __restrict__ ar16, const float* __restrict__ arsum,
    float* __restrict__ prep)
{
    __shared__ unsigned long long pu_s8[2][16][32];   // 8 KB, XOR-swizzled
    __shared__ unsigned arn_s[16][145];               // 9.3 KB (odd stride)
    __shared__ float red_s[2][256];                   // 2 KB

    const int bl0 = blockIdx.x * 16;
    const int jp  = blockIdx.y;
    const int z   = blockIdx.z;
    const int tid = threadIdx.x;
    const int w = tid >> 6, lane = tid & 63;
    const int jl = w >> 1, h = w & 1;
    const int g = lane >> 4, d = lane & 15;
    const int jg = jp * 2 + jl;
    const int gh = g >> 1, co = (g & 1) * 8;

    for (int t = tid; t < 2304; t += 256) {
        int blr = t / 144, nl = t - blr * 144;
        arn_s[blr][nl] = *reinterpret_cast<const unsigned*>(
            ar16 + (((size_t)(bl0 + blr)) * KKA + z * 144 + nl) * 32 + jp * 2);
    }

    f32x4 acc0 = {0.f, 0.f, 0.f, 0.f}, acc1 = {0.f, 0.f, 0.f, 0.f};

    for (int ci = 0; ci < 9; ++ci) {
        __syncthreads();
        #pragma unroll
        for (int k = 0; k < 4; ++k) {
            int idx = tid + k * 256;
            int half = idx >> 9, r = idx & 511;
            int nl8 = r >> 6, blr = (r >> 2) & 15, q4 = r & 3;
            uint2 v = *reinterpret_cast<const uint2*>(
                pu16 + (((size_t)(bl0 + blr)) * KKA + z * 144 + half * 72 + ci * 8 + nl8) * 16 + q4 * 4);
            pu_s8[half][blr][(nl8 * 4 + q4) ^ ((blr & 7) << 1)] =
                __builtin_bit_cast(unsigned long long, v);
        }
        __syncthreads();
        #pragma unroll
        for (int sp = 0; sp < 4; ++sp) {
            const int nl = h * 72 + ci * 8 + sp * 2 + gh;
            const int n  = z * 144 + nl;
            uint4 a4 = *reinterpret_cast<const uint4*>(
                W1b + ((size_t)n * 512 + jg * 16 + d) * 16 + co);
            unsigned av = arn_s[d][nl];
            float s = jl ? bhi(av) : blo(av);
            int byteoff = (sp * 64 + g * 16) ^ ((d & 7) << 4);
            uint4 p4 = *reinterpret_cast<const uint4*>(
                reinterpret_cast<const char*>(&pu_s8[h][d][0]) + byteoff);
            uint4 bb;
            bb.x = cvtpk(blo(p4.x) * s, bhi(p4.x) * s);
            bb.y = cvtpk(blo(p4.y) * s, bhi(p4.y) * s);
            bb.z = cvtpk(blo(p4.z) * s, bhi(p4.z) * s);
            bb.w = cvtpk(blo(p4.w) * s, bhi(p4.w) * s);
            bf16x8 af = __builtin_bit_cast(bf16x8, a4);
            bf16x8 bf = __builtin_bit_cast(bf16x8, bb);
            if (sp & 1) acc1 = __builtin_amdgcn_mfma_f32_16x16x32_bf16(af, bf, acc1, 0, 0, 0);
            else        acc0 = __builtin_amdgcn_mfma_f32_16x16x32_bf16(af, bf, acc0, 0, 0, 0);
        }
    }

    f32x4 acc = acc0 + acc1;
    __syncthreads();
    if (h == 1) {
        #pragma unroll
        for (int i = 0; i < 4; ++i)
            red_s[jl][(g * 4 + i) * 16 + d] = acc[i];
    }
    __syncthreads();
    if (h == 0) {
        const float inv = 1.0f / arsum[((size_t)(bl0 + d)) * 32 + jg];
        #pragma unroll
        for (int i = 0; i < 4; ++i) {
            float vv = (acc[i] + red_s[jl][(g * 4 + i) * 16 + d]) * inv;
            prep[((size_t)z * 512 + jg * 16 + g * 4 + i) * NBL + bl0 + d] = vv;
        }
    }
}

// ---------------------------------------------------------------------------
// Kernel 5: BatchNorm (batch stats, biased var) + layout to [b, 512, 6, 6].
// ---------------------------------------------------------------------------
__global__ __launch_bounds__(256) void k_bn(
    const float* __restrict__ prep, const float* __restrict__ gamma,
    const float* __restrict__ beta, float* __restrict__ out_pose)
{
    const int tid = threadIdx.x;
    const int wid = tid >> 6, lane = tid & 63;
    const int ch  = blockIdx.x * 4 + wid;
    const float* p0 = prep + (size_t)ch * NBL;
    const float* p1 = p0 + 294912;   // z=1 plane

    float sum = 0.f, sq = 0.f;
    float v[9];
    #pragma unroll
    for (int k = 0; k < 9; ++k) {
        int i = lane + k * 64;
        float x = p0[i] + p1[i];
        v[k] = x;
        sum += x;
        sq  += x * x;
    }
    #pragma unroll
    for (int msk = 32; msk >= 1; msk >>= 1) {
        sum += __shfl_xor(sum, msk);
        sq  += __shfl_xor(sq, msk);
    }
    const float mean = sum * (1.f / 576.f);
    const float var  = sq * (1.f / 576.f) - mean * mean;
    const float inv  = rsqrtf(var + 1e-5f);
    const float sc   = gamma[ch] * inv;
    const float sh   = beta[ch] - mean * sc;
    #pragma unroll
    for (int k = 0; k < 9; ++k) {
        int i = lane + k * 64;
        int b = i / 36;
        int l = i - b * 36;
        out_pose[(size_t)b * 18432 + (size_t)ch * 36 + l] = v[k] * sc + sh;
    }
}

extern "C" void kernel_launch(void* const* d_in, const int* in_sizes, int n_in,
                              void* d_out, int out_size, void* d_ws, size_t ws_size,
                              hipStream_t stream)
{
    const float* a     = (const float*)d_in[0];
    const float* pose  = (const float*)d_in[1];
    const float* W1    = (const float*)d_in[2];
    const float* W2    = (const float*)d_in[3];
    const float* b2    = (const float*)d_in[4];
    const float* gamma = (const float*)d_in[5];
    const float* beta  = (const float*)d_in[6];
    float* out      = (float*)d_out;
    float* out_a    = out;              // [16, 32, 6, 6]
    float* out_pose = out + 18432;      // [16, 512, 6, 6]

    unsigned short* wsu = (unsigned short*)d_ws;
    unsigned short* W1b   = wsu + W1B_OFF;
    unsigned short* W2b   = wsu + W2B_OFF;
    unsigned short* pu16  = wsu + PU16_OFF;
    unsigned short* ar16  = wsu + AR16_OFF;
    float* wsf    = (float*)((char*)d_ws + FREG_BYTE);
    float* auf    = wsf + AU_F;
    float* arsump = wsf + ARSUMP_F;
    float* arsumv = wsf + ARSUM_F;
    float* prep   = wsf + PREP_F;

    hipLaunchKernelGGL(k_cvt, dim3(1224), dim3(256), 0, stream, W1, W2, W1b, W2b);
    hipLaunchKernelGGL(k_gather, dim3(512), dim3(256), 0, stream, a, pose, pu16, auf);
    hipLaunchKernelGGL(k_logit, dim3(36, 9), dim3(256), 0, stream,
                       W2b, pu16, b2, auf, ar16, arsump);
    hipLaunchKernelGGL(k_finish, dim3(144), dim3(256), 0, stream,
                       arsump, auf, arsumv, out_a);
    hipLaunchKernelGGL(k_pose, dim3(36, 16, 2), dim3(256), 0, stream,
                       W1b, pu16, ar16, arsumv, prep);
    hipLaunchKernelGGL(k_bn, dim3(128), dim3(256), 0, stream,
                       prep, gamma, beta, out_pose);
}